// Round 12
// baseline (287.908 us; speedup 1.0000x reference)
//
#include <hip/hip_runtime.h>
#include <hip/hip_bf16.h>
#include <math.h>

// Problem constants (fixed by the reference)
constexpr int T_LEN = 2048;
constexpr int B_SZ  = 2;
constexpr int D_DIM = 768;
constexpr int H_NUM = 8;
constexpr int HD    = 96;        // D/H
constexpr int FFN   = 3072;
constexpr float EPS = 1e-5f;
constexpr int TB    = T_LEN * B_SZ;   // 4096 rows
constexpr int QKV_LD = 3 * D_DIM;     // 2304
constexpr int NSPLIT = 4;             // attention split-K factor
constexpr int CHUNK  = T_LEN / NSPLIT;   // 512 keys per block
// (1/sqrt(96)) * log2(e): folded into wq/bq so softmax is a bare v_exp (2^x)
constexpr float SC_LOG2E = 0.14724444458547f;

typedef __attribute__((ext_vector_type(8)))  short short8;
typedef __attribute__((ext_vector_type(4)))  short short4v;
typedef __attribute__((ext_vector_type(2)))  short short2v;
typedef __attribute__((ext_vector_type(4)))  float f32x4;
typedef __attribute__((ext_vector_type(16))) float f32x16;
typedef __attribute__((ext_vector_type(2)))  int   int2v;

__device__ __forceinline__ short f2bf(float f) {
    union { float f; unsigned u; } v; v.f = f;
    return (short)((v.u + 0x7FFFu + ((v.u >> 16) & 1u)) >> 16);   // RNE
}
__device__ __forceinline__ float bf2f(short s) {
    union { unsigned u; float f; } v;
    v.u = ((unsigned)(unsigned short)s) << 16;
    return v.f;
}
// packed f32x2 -> bf16x2 (V_CVT_PK_BF16_F32 on gfx950); a in low half
__device__ __forceinline__ unsigned pkbf(float a, float b) {
    union { __hip_bfloat162 h; unsigned u; } v;
    v.h = __float22bfloat162_rn(make_float2(a, b));
    return v.u;
}
__device__ __forceinline__ short4v pk4(float a, float b, float c, float d) {
    union { unsigned u[2]; short4v s; } v;
    v.u[0] = pkbf(a, b); v.u[1] = pkbf(c, d);
    return v.s;
}
__device__ __forceinline__ short8 mk8(int a, int b, int c, int d) {
    union { int u[4]; short8 s; } v;
    v.u[0] = a; v.u[1] = b; v.u[2] = c; v.u[3] = d;
    return v.s;
}

// async global->LDS, 16B per lane; LDS dst = wave-uniform base + lane*16
__device__ __forceinline__ void async_ld16(const short* g, short* l) {
    __builtin_amdgcn_global_load_lds(
        (const __attribute__((address_space(1))) unsigned int*)g,
        (__attribute__((address_space(3))) unsigned int*)l, 16, 0, 0);
}

// ---------------------------------------------------------------------------
// Prep: fused fp32 -> bf16 conversion over 7 segments (x + 6 weight blobs),
// with a per-segment scale (wq is pre-scaled by SC_LOG2E so attention's
// softmax exp becomes a bare v_exp_f32).
// ---------------------------------------------------------------------------
struct CvtArgs {
    const float* src[7];
    short*       dst[7];
    float        scl[7];
    int          end4[7];   // cumulative segment ends, in float4 units
};

__global__ __launch_bounds__(256)
void cvt_all(CvtArgs a, int total4) {
    const int i = blockIdx.x * 256 + threadIdx.x;
    if (i >= total4) return;
    int s = 0;
    while (i >= a.end4[s]) ++s;
    const int base = s ? a.end4[s - 1] : 0;
    const int j = i - base;
    const float sc = a.scl[s];
    const float4 v = ((const float4*)a.src[s])[j];
    short4v o;
    o[0] = f2bf(v.x * sc); o[1] = f2bf(v.y * sc);
    o[2] = f2bf(v.z * sc); o[3] = f2bf(v.w * sc);
    *(short4v*)(a.dst[s] + (size_t)j * 4) = o;
}

__global__ __launch_bounds__(256)
void concat_bias(const float* __restrict__ bq, const float* __restrict__ bk,
                 const float* __restrict__ bv, float* __restrict__ dst) {
    const int i = blockIdx.x * 256 + threadIdx.x;
    if (i >= QKV_LD) return;
    dst[i] = (i < 768) ? bq[i] * SC_LOG2E : (i < 1536 ? bk[i - 768] : bv[i - 1536]);
}

// ---------------------------------------------------------------------------
// bf16 MFMA GEMM: C[M,N] = A[M,K] @ W[N,K]^T + bias[N]  (optional ReLU)
// Validated stack: LDS XOR-swizzle (R9), 3-stage counted-vmcnt pipeline (R8),
// XCD-aware bijective tile remap (R10, ~-18us aggregate).
// R12: SPLITK template. The skinny-N GEMMs (Wo, FFN2: N=768 -> only 768
// blocks = 3/CU, latency-bound K-loop) split K across blockIdx.z: 2x blocks
// (6/CU), half the K-steps per block. Partials stay f32 (z stride M*N);
// bias added on z==0 only. The downstream ln_residual sums the partials --
// no extra combine kernel, and f32 partials are MORE accurate than the old
// bf16-rounded single output.
// ---------------------------------------------------------------------------
template <int BM, int BN, int BK, int SPLITK, typename OutT, bool RELU>
__global__ __launch_bounds__(256)
void gemm_mfma(const short* __restrict__ A, const short* __restrict__ W,
               const float* __restrict__ bias, OutT* __restrict__ C,
               int M, int N, int K) {
    constexpr int MI = BM / 32;   // 16-row tiles per wave
    constexpr int NI = BN / 32;   // 16-col tiles per wave
    constexpr int KI = BK / 32;   // k-substeps per tile
    static_assert(BM * BK == 4096 && BN * BK == 4096, "4 glds/thread/stage");
    constexpr int ROWSTEP = 2048 / BK;   // rows per 2048-short chunk
    __shared__ __align__(16) short As[3][4096];
    __shared__ __align__(16) short Bs[3][4096];

    const int tid  = threadIdx.x;
    const int w    = tid >> 6;
    const int lane = tid & 63;
    const int l16  = lane & 15;
    const int q4   = lane >> 4;          // 0..3
    const int z    = blockIdx.z;         // split-K slice
    const int Ksub = K / SPLITK;

    // XCD-aware bijective tile remap (x,y grids here are all %8 == 0)
    const int gx  = N / BN;
    const int nwg = gx * (M / BM);
    const int lid = blockIdx.x + blockIdx.y * gx;
    const int tile = (lid & 7) * (nwg >> 3) + (lid >> 3);
    const int row0 = (tile / gx) * BM;
    const int col0 = (tile % gx) * BN;

    const int wm   = (w >> 1) * (BM / 2); // wave m-offset in tile
    const int wn   = (w & 1) * (BN / 2);  // wave n-offset in tile

    // swizzled LDS offset (in shorts) of 16B slot j in row r
    auto lds_off = [&](int r, int j) {
        const int xt = (BK == 64) ? (r & 7) : ((r >> 1) & 3);
        return r * BK + (j ^ xt) * 8;
    };

    // staging: thread tid owns LDS slot (row mA, slot sA) of each chunk;
    // load the GLOBAL column that belongs in that swizzled slot.
    const int mA = tid / (BK / 8);
    const int sA = tid % (BK / 8);
    const int xtA = (BK == 64) ? (mA & 7) : ((mA >> 1) & 3);
    const int kA = (sA ^ xtA) * 8;
    const short* gA0 = A + (size_t)(row0 + mA) * K + z * Ksub + kA;
    const short* gA1 = gA0 + (size_t)ROWSTEP * K;
    const short* gB0 = W + (size_t)(col0 + mA) * K + z * Ksub + kA;
    const short* gB1 = gB0 + (size_t)ROWSTEP * K;

    f32x4 acc[MI][NI];
#pragma unroll
    for (int mi = 0; mi < MI; ++mi)
#pragma unroll
        for (int ni = 0; ni < NI; ++ni)
#pragma unroll
            for (int r = 0; r < 4; ++r) acc[mi][ni][r] = 0.f;

    auto stage = [&](int buf) {
        async_ld16(gA0, &As[buf][w * 512]);
        async_ld16(gA1, &As[buf][2048 + w * 512]);
        async_ld16(gB0, &Bs[buf][w * 512]);
        async_ld16(gB1, &Bs[buf][2048 + w * 512]);
        gA0 += BK; gA1 += BK; gB0 += BK; gB1 += BK;
    };
    auto compute = [&](int buf) {
#pragma unroll
        for (int ks = 0; ks < KI; ++ks) {
            short8 af[MI], bfr[NI];
#pragma unroll
            for (int mi = 0; mi < MI; ++mi)
                af[mi] = *(const short8*)&As[buf][lds_off(wm + mi * 16 + l16, ks * 4 + q4)];
#pragma unroll
            for (int ni = 0; ni < NI; ++ni)
                bfr[ni] = *(const short8*)&Bs[buf][lds_off(wn + ni * 16 + l16, ks * 4 + q4)];
#pragma unroll
            for (int mi = 0; mi < MI; ++mi)
#pragma unroll
                for (int ni = 0; ni < NI; ++ni)
                    acc[mi][ni] = __builtin_amdgcn_mfma_f32_16x16x32_bf16(
                        af[mi], bfr[ni], acc[mi][ni], 0, 0, 0);
        }
    };

    const int NT = Ksub / BK;
    stage(0);                            // prologue: tiles 0,1 in flight
    stage(1);
    int cur = 0;                         // rotating buffer index (t % 3)
    for (int t = 0; t < NT; ++t) {
        if (t + 2 < NT) {
            int nb = cur + 2; if (nb >= 3) nb -= 3;
            stage(nb);                   // 12 outstanding
            asm volatile("s_waitcnt vmcnt(8)" ::: "memory");  // tile t done
        } else if (t + 1 < NT) {
            asm volatile("s_waitcnt vmcnt(4)" ::: "memory");  // tile t done
        } else {
            asm volatile("s_waitcnt vmcnt(0)" ::: "memory");  // final drain
        }
        __builtin_amdgcn_s_barrier();    // all waves: buf[cur] fully written
        __builtin_amdgcn_sched_barrier(0);
        compute(cur);
        __builtin_amdgcn_s_barrier();    // all waves: buf[cur] fully read
        __builtin_amdgcn_sched_barrier(0);
        if (++cur == 3) cur = 0;
    }

    OutT* Cz = C + (size_t)z * M * N;     // partial slice (SPLITK>1)
    float bcol[NI];
#pragma unroll
    for (int ni = 0; ni < NI; ++ni)
        bcol[ni] = (SPLITK == 1 || z == 0) ? bias[col0 + wn + ni * 16 + l16] : 0.f;
#pragma unroll
    for (int mi = 0; mi < MI; ++mi) {
#pragma unroll
        for (int r = 0; r < 4; ++r) {
            const int row = row0 + wm + mi * 16 + q4 * 4 + r;
#pragma unroll
            for (int ni = 0; ni < NI; ++ni) {
                float v = acc[mi][ni][r] + bcol[ni];
                if (RELU) v = fmaxf(v, 0.f);
                const int col = col0 + wn + ni * 16 + l16;
                if constexpr (sizeof(OutT) == 2)
                    Cz[(size_t)row * N + col] = (OutT)f2bf(v);
                else
                    Cz[(size_t)row * N + col] = v;
            }
        }
    }
}

// ---------------------------------------------------------------------------
// MFMA bf16 flash attention v7 (frozen control): transposed PV +
// in-register P + double-buffered K/V LDS, 1 barrier/iter.
// ---------------------------------------------------------------------------
__global__ __launch_bounds__(256)
void attn_mfma(const short* __restrict__ qkv, short* __restrict__ Opart,
               float* __restrict__ lpart) {
    __shared__ short Ks[2][2][32][56];  // [buf][d-half][key][d%48], conflict-free
    __shared__ short Vt[2][96][44];     // [buf][d][key], stride 44

    const int tid  = threadIdx.x;
    const int w    = tid >> 6;
    const int lane = tid & 63;
    const int l31  = lane & 31;
    const int h5   = lane >> 5;
    const int t0   = blockIdx.x * 128;
    const int bh   = blockIdx.y;
    const int split = blockIdx.z;
    const int b    = bh >> 3;
    const int h    = bh & 7;

    // Q fragments straight from global bf16 (wave-private 32 q-rows)
    short8 qf[6];
    {
        const int qrow = t0 + w * 32 + l31;
        const short* qb = qkv + ((size_t)qrow * B_SZ + b) * QKV_LD + h * HD;
#pragma unroll
        for (int ks = 0; ks < 6; ++ks)
            qf[ks] = *(const short8*)&qb[ks * 16 + h5 * 8];
    }

    // --- staging assignments (wave-specialized), chunk-local keys ---
    const int k_row = tid >> 2;                   // 0..31 (valid for tid<128)
    const int k_q   = tid & 3;                    // d-quarter
    const short* gK = qkv + ((size_t)(split * CHUNK + k_row) * B_SZ + b) * QKV_LD
                      + D_DIM + h * HD + k_q * 24;
    const int ll = tid - 128;
    const int dg = (ll & 7) * 12;                 // d-group
    const int kg = (ll >> 3) * 2;                 // key pair
    const short* gV = qkv + ((size_t)(split * CHUNK + kg) * B_SZ + b) * QKV_LD
                      + 2 * D_DIM + h * HD + dg;
    const size_t step  = (size_t)32 * B_SZ * QKV_LD;
    const size_t vrow  = (size_t)B_SZ * QKV_LD;   // one key row

    f32x16 oacc[3];
#pragma unroll
    for (int nt = 0; nt < 3; ++nt)
#pragma unroll
        for (int r = 0; r < 16; ++r) oacc[nt][r] = 0.f;
    float dsum = 0.f;

    short8  kpf[3];
    short4v vpf[2][3];
    auto prefetch = [&](int t) {
        const size_t off = (size_t)t * step;
        if (w < 2) {
#pragma unroll
            for (int j = 0; j < 3; ++j)
                kpf[j] = *(const short8*)(gK + off + j * 8);
        } else {
#pragma unroll
            for (int r = 0; r < 2; ++r)
#pragma unroll
                for (int c = 0; c < 3; ++c)
                    vpf[r][c] = *(const short4v*)(gV + off + r * vrow + c * 4);
        }
    };
    auto lds_write = [&](int buf) {
        if (w < 2) {
#pragma unroll
            for (int j = 0; j < 3; ++j)
                *(short8*)&Ks[buf][k_q >> 1][k_row][(k_q & 1) * 24 + j * 8] = kpf[j];
        } else {
#pragma unroll
            for (int d = 0; d < 12; ++d) {
                short2v t;
                t[0] = vpf[0][d >> 2][d & 3];
                t[1] = vpf[1][d >> 2][d & 3];
                *(short2v*)&Vt[buf][dg + d][kg] = t;
            }
        }
    };

    constexpr int NIT = CHUNK / 32;   // 16
    prefetch(0);
    lds_write(0);        // tile 0 -> buf0 (no prior readers)
    prefetch(1);

    for (int it = 0; it < NIT; ++it) {
        __syncthreads();   // buf[it&1] writes visible; buf[(it+1)&1] readers done
        if (it + 1 < NIT) lds_write((it + 1) & 1);   // overlaps this tile's MFMA
        if (it + 2 < NIT) prefetch(it + 2);          // HBM latency under compute
        const int pb = it & 1;

        // S^T = K.Q^T (swapped operands; Q pre-scaled by scale*log2e).
        // sa[r] = S[q=l31][key=(r&3)+8*(r>>2)+4*h5]
        f32x16 sa;
#pragma unroll
        for (int r = 0; r < 16; ++r) sa[r] = 0.f;
        __builtin_amdgcn_s_setprio(1);
#pragma unroll
        for (int ks = 0; ks < 6; ++ks) {
            const int half = ks / 3;                   // compile-time per ks
            const int base = ks * 16 - half * 48;      // local d within half
            const short8 kf = *(const short8*)&Ks[pb][half][l31][base + h5 * 8];
            sa = __builtin_amdgcn_mfma_f32_32x32x16_bf16(kf, qf[ks], sa, 0, 0, 0);
        }
        __builtin_amdgcn_s_setprio(0);

        // P = 2^S (bare v_exp), fully in-register
        float pvx[16];
#pragma unroll
        for (int r = 0; r < 16; ++r) pvx[r] = __builtin_amdgcn_exp2f(sa[r]);
        // denominator partial (this lane's 16 keys of the tile)
        dsum += ((pvx[0] + pvx[1]) + (pvx[2] + pvx[3]))
              + ((pvx[4] + pvx[5]) + (pvx[6] + pvx[7]))
              + ((pvx[8] + pvx[9]) + (pvx[10] + pvx[11]))
              + ((pvx[12] + pvx[13]) + (pvx[14] + pvx[15]));

        // pack to bf16 + permlane32_swap -> P^T B-fragments (keys 0..15, 16..31)
        int wA0 = (int)pkbf(pvx[0],  pvx[1]);
        int wA1 = (int)pkbf(pvx[2],  pvx[3]);
        int wA2 = (int)pkbf(pvx[4],  pvx[5]);
        int wA3 = (int)pkbf(pvx[6],  pvx[7]);
        int wB0 = (int)pkbf(pvx[8],  pvx[9]);
        int wB1 = (int)pkbf(pvx[10], pvx[11]);
        int wB2 = (int)pkbf(pvx[12], pvx[13]);
        int wB3 = (int)pkbf(pvx[14], pvx[15]);
        const int2v s0 = __builtin_amdgcn_permlane32_swap(wA0, wA2, false, false);
        const int2v s1 = __builtin_amdgcn_permlane32_swap(wA1, wA3, false, false);
        const int2v s2 = __builtin_amdgcn_permlane32_swap(wB0, wB2, false, false);
        const int2v s3 = __builtin_amdgcn_permlane32_swap(wB1, wB3, false, false);
        const short8 pf0 = mk8(s0[0], s1[0], s0[1], s1[1]);  // keys 0..15
        const short8 pf1 = mk8(s2[0], s3[0], s2[1], s3[1]);  // keys 16..31

        // O^T += V^T . P^T  (3 d-tiles of 32)
        __builtin_amdgcn_s_setprio(1);
#pragma unroll
        for (int ks2 = 0; ks2 < 2; ++ks2) {
            const short8 pfr = ks2 ? pf1 : pf0;
#pragma unroll
            for (int nt = 0; nt < 3; ++nt) {
                const short* vp = &Vt[pb][nt * 32 + l31][ks2 * 16 + h5 * 8];
                const short4v vlo = *(const short4v*)vp;
                const short4v vhi = *(const short4v*)(vp + 4);
                const short8 vf = __builtin_shufflevector(vlo, vhi, 0, 1, 2, 3, 4, 5, 6, 7);
                oacc[nt] = __builtin_amdgcn_mfma_f32_32x32x16_bf16(vf, pfr, oacc[nt], 0, 0, 0);
            }
        }
        __builtin_amdgcn_s_setprio(0);
    }

    // epilogue: lane l31 = q-row; oacc[nt][r] = O^T[d=nt*32+(r&3)+8*(r>>2)+4*h5][q]
    const float other = __shfl_xor(dsum, 32);
    const float denom = dsum + other;
    const int qrow = t0 + w * 32 + l31;
    const int grow = qrow * B_SZ + b;
    short* op = Opart + ((size_t)split * TB + grow) * D_DIM + h * HD;
#pragma unroll
    for (int nt = 0; nt < 3; ++nt)
#pragma unroll
        for (int g = 0; g < 4; ++g)
            *(short4v*)&op[nt * 32 + g * 8 + h5 * 4] =
                pk4(oacc[nt][4 * g], oacc[nt][4 * g + 1],
                    oacc[nt][4 * g + 2], oacc[nt][4 * g + 3]);
    if (lane < 32)
        lpart[((size_t)split * TB + grow) * H_NUM + h] = denom;
}

// ---------------------------------------------------------------------------
// Combine: ctx = (sum_c Opart[c]) / (sum_c lpart[c]).  One block per row,
// 192 active lanes x 4 d each, short4 vector loads.
// ---------------------------------------------------------------------------
__global__ __launch_bounds__(256)
void attn_combine(const short* __restrict__ Opart, const float* __restrict__ lpart,
                  short* __restrict__ ctx) {
    const int row = blockIdx.x;
    const int tid = threadIdx.x;
    if (tid >= 192) return;
    const int d = tid * 4;
    const int h = d / 96;
    float o0 = 0.f, o1 = 0.f, o2 = 0.f, o3 = 0.f, l = 0.f;
#pragma unroll
    for (int c = 0; c < NSPLIT; ++c) {
        const short4v v = *(const short4v*)&Opart[((size_t)c * TB + row) * D_DIM + d];
        o0 += bf2f(v[0]); o1 += bf2f(v[1]); o2 += bf2f(v[2]); o3 += bf2f(v[3]);
        l += lpart[((size_t)c * TB + row) * H_NUM + h];
    }
    const float iv = 1.f / l;
    short4v r;
    r[0] = f2bf(o0 * iv); r[1] = f2bf(o1 * iv);
    r[2] = f2bf(o2 * iv); r[3] = f2bf(o3 * iv);
    *(short4v*)&ctx[(size_t)row * D_DIM + d] = r;
}

// ---------------------------------------------------------------------------
// Fused residual + LayerNorm + split-K combine:
// out = LN(xres + y0 + y1)*g + b, where y0/y1 are the two f32 GEMM partials.
// ---------------------------------------------------------------------------
template <typename XT, typename OT>
__global__ __launch_bounds__(256)
void ln_residual(const XT* __restrict__ xres, const float* __restrict__ y0,
                 const float* __restrict__ y1,
                 const float* __restrict__ g, const float* __restrict__ bb,
                 OT* __restrict__ out) {
    const int row = blockIdx.x;
    const int tid = threadIdx.x;
    const XT*    xr = xres + (size_t)row * D_DIM;
    const float* y0r = y0 + (size_t)row * D_DIM;
    const float* y1r = y1 + (size_t)row * D_DIM;

    float vals[3];
    float s = 0.f, s2 = 0.f;
#pragma unroll
    for (int i = 0; i < 3; ++i) {
        const int d = tid + i * 256;
        float xv;
        if constexpr (sizeof(XT) == 2) xv = bf2f((short)xr[d]);
        else                           xv = (float)xr[d];
        const float t = xv + y0r[d] + y1r[d];
        vals[i] = t;
        s += t;
        s2 = fmaf(t, t, s2);
    }
#pragma unroll
    for (int off = 32; off > 0; off >>= 1) {
        s  += __shfl_down(s, off);
        s2 += __shfl_down(s2, off);
    }
    __shared__ float red_s[4], red_s2[4];
    const int wid = tid >> 6, lane = tid & 63;
    if (lane == 0) { red_s[wid] = s; red_s2[wid] = s2; }
    __syncthreads();
    __shared__ float sh_mean, sh_rstd;
    if (tid == 0) {
        const float ts  = red_s[0] + red_s[1] + red_s[2] + red_s[3];
        const float ts2 = red_s2[0] + red_s2[1] + red_s2[2] + red_s2[3];
        const float mean = ts * (1.f / D_DIM);
        const float var  = ts2 * (1.f / D_DIM) - mean * mean;
        sh_mean = mean;
        sh_rstd = rsqrtf(var + EPS);
    }
    __syncthreads();
    const float mean = sh_mean, rstd = sh_rstd;
#pragma unroll
    for (int i = 0; i < 3; ++i) {
        const int d = tid + i * 256;
        const float o = (vals[i] - mean) * rstd * g[d] + bb[d];
        if constexpr (sizeof(OT) == 2)
            out[(size_t)row * D_DIM + d] = (OT)f2bf(o);
        else
            out[(size_t)row * D_DIM + d] = o;
    }
}

// ---------------------------------------------------------------------------
// Launch
// ---------------------------------------------------------------------------
extern "C" void kernel_launch(void* const* d_in, const int* in_sizes, int n_in,
                              void* d_out, int out_size, void* d_ws, size_t ws_size,
                              hipStream_t stream) {
    const float* x     = (const float*)d_in[0];
    const float* wq    = (const float*)d_in[1];
    const float* bq    = (const float*)d_in[2];
    const float* wk    = (const float*)d_in[3];
    const float* bk    = (const float*)d_in[4];
    const float* wv    = (const float*)d_in[5];
    const float* bv    = (const float*)d_in[6];
    const float* wo    = (const float*)d_in[7];
    const float* bo    = (const float*)d_in[8];
    const float* ln1g  = (const float*)d_in[9];
    const float* ln1b  = (const float*)d_in[10];
    const float* w1    = (const float*)d_in[11];
    const float* b1    = (const float*)d_in[12];
    const float* w2    = (const float*)d_in[13];
    const float* b2    = (const float*)d_in[14];
    const float* ln2g  = (const float*)d_in[15];
    const float* ln2b  = (const float*)d_in[16];
    float* out = (float*)d_out;

    // workspace layout (bytes) — total 71,312,384 (< 75.5 MB proven in R1)
    char* ws = (char*)d_ws;
    short* qkvb  = (short*)(ws + 0);             // [TB,2304] bf16  0 .. 18,874,368
    short* ctxb  = (short*)(ws + 18874368);      // [TB,768]  bf16  .. 25,165,824
    short* hb    = (short*)(ws + 0);             // [TB,3072] bf16  (reuses qkvb+ctxb)
    short* xb    = (short*)(ws + 25165824);      // [TB,768]  bf16  .. 31,457,280
    short* Opart = (short*)(ws + 25165824);      // 4x[TB,768] bf16 .. 50,331,648 (over xb)
    float* lpart = (float*)(ws + 50331648);      // 4x[TB,8]  f32   .. 50,855,936
    float* tmpf  = (float*)(ws + 25165824);      // 2x[TB,768] f32  .. 50,331,648 (over dead Opart)
    short* x1b   = (short*)(ws + 50855936);      // [TB,768]  bf16  .. 57,147,392
    short* wqkv  = (short*)(ws + 57147392);      // [2304,768] bf16 .. 60,686,336
    short* wob   = (short*)(ws + 60686336);      // [768,768]  bf16 .. 61,865,984
    short* w1b   = (short*)(ws + 61865984);      // [3072,768] bf16 .. 66,584,576
    short* w2b   = (short*)(ws + 66584576);      // [768,3072] bf16 .. 71,303,168
    float* bqkv  = (float*)(ws + 71303168);      // [2304] f32      .. 71,312,384
    float* tmpf1 = tmpf + (size_t)TB * D_DIM;    // second split-K partial

    // fused fp32->bf16 conversions (wq pre-scaled by scale*log2e)
    CvtArgs ca;
    ca.src[0] = x;  ca.dst[0] = xb;   ca.scl[0] = 1.f;
    ca.src[1] = wq; ca.dst[1] = wqkv; ca.scl[1] = SC_LOG2E;
    ca.src[2] = wk; ca.dst[2] = wqkv + 768 * 768;     ca.scl[2] = 1.f;
    ca.src[3] = wv; ca.dst[3] = wqkv + 2 * 768 * 768; ca.scl[3] = 1.f;
    ca.src[4] = wo; ca.dst[4] = wob;  ca.scl[4] = 1.f;
    ca.src[5] = w1; ca.dst[5] = w1b;  ca.scl[5] = 1.f;
    ca.src[6] = w2; ca.dst[6] = w2b;  ca.scl[6] = 1.f;
    const int n4[7] = {TB * D_DIM / 4, 768 * 768 / 4, 768 * 768 / 4, 768 * 768 / 4,
                       768 * 768 / 4, FFN * 768 / 4, 768 * FFN / 4};
    int acc4 = 0;
    for (int i = 0; i < 7; ++i) { acc4 += n4[i]; ca.end4[i] = acc4; }
    cvt_all<<<(acc4 + 255) / 256, 256, 0, stream>>>(ca, acc4);
    concat_bias<<<(QKV_LD + 255) / 256, 256, 0, stream>>>(bq, bk, bv, bqkv);

    // fused QKV projection: [TB,2304] = xb @ wqkv^T + bqkv (576 blocks, %8==0)
    gemm_mfma<128, 128, 32, 1, short, false><<<dim3(QKV_LD / 128, TB / 128), 256, 0, stream>>>(
        xb, wqkv, bqkv, qkvb, TB, QKV_LD, D_DIM);

    // attention (v7, frozen) + combine
    attn_mfma<<<dim3(T_LEN / 128, B_SZ * H_NUM, NSPLIT), dim3(256), 0, stream>>>(
        qkvb, Opart, lpart);
    attn_combine<<<dim3(TB), 256, 0, stream>>>(Opart, lpart, ctxb);

    // out projection: SPLITK=2 -> 1536 blocks, 6 K-steps each, f32 partials
    gemm_mfma<64, 64, 64, 2, float, false><<<dim3(D_DIM / 64, TB / 64, 2), 256, 0, stream>>>(
        ctxb, wob, bo, tmpf, TB, D_DIM, D_DIM);
    ln_residual<float, short><<<dim3(TB), 256, 0, stream>>>(x, tmpf, tmpf1, ln1g, ln1b, x1b);

    // FFN1 (768 blocks, control)
    gemm_mfma<128, 128, 32, 1, short, true><<<dim3(FFN / 128, TB / 128), 256, 0, stream>>>(
        x1b, w1b, b1, hb, TB, FFN, D_DIM);
    // FFN2: SPLITK=2 -> 1536 blocks, 24 K-steps each (was 48), f32 partials
    gemm_mfma<64, 64, 64, 2, float, false><<<dim3(D_DIM / 64, TB / 64, 2), 256, 0, stream>>>(
        hb, w2b, b2, tmpf, TB, D_DIM, FFN);
    ln_residual<short, float><<<dim3(TB), 256, 0, stream>>>(x1b, tmpf, tmpf1, ln2g, ln2b, out);
}

// Round 13
// 278.777 us; speedup vs baseline: 1.0328x; 1.0328x over previous
//
#include <hip/hip_runtime.h>
#include <hip/hip_bf16.h>
#include <math.h>

// Problem constants (fixed by the reference)
constexpr int T_LEN = 2048;
constexpr int B_SZ  = 2;
constexpr int D_DIM = 768;
constexpr int H_NUM = 8;
constexpr int HD    = 96;        // D/H
constexpr int FFN   = 3072;
constexpr float EPS = 1e-5f;
constexpr int TB    = T_LEN * B_SZ;   // 4096 rows
constexpr int QKV_LD = 3 * D_DIM;     // 2304
constexpr int NSPLIT = 4;             // attention split-K factor
constexpr int CHUNK  = T_LEN / NSPLIT;   // 512 keys per block
// (1/sqrt(96)) * log2(e): folded into wq/bq so softmax is a bare v_exp (2^x)
constexpr float SC_LOG2E = 0.14724444458547f;

typedef __attribute__((ext_vector_type(8)))  short short8;
typedef __attribute__((ext_vector_type(4)))  short short4v;
typedef __attribute__((ext_vector_type(2)))  short short2v;
typedef __attribute__((ext_vector_type(4)))  float f32x4;
typedef __attribute__((ext_vector_type(16))) float f32x16;
typedef __attribute__((ext_vector_type(2)))  int   int2v;

__device__ __forceinline__ short f2bf(float f) {
    union { float f; unsigned u; } v; v.f = f;
    return (short)((v.u + 0x7FFFu + ((v.u >> 16) & 1u)) >> 16);   // RNE
}
__device__ __forceinline__ float bf2f(short s) {
    union { unsigned u; float f; } v;
    v.u = ((unsigned)(unsigned short)s) << 16;
    return v.f;
}
// packed f32x2 -> bf16x2 (V_CVT_PK_BF16_F32 on gfx950); a in low half
__device__ __forceinline__ unsigned pkbf(float a, float b) {
    union { __hip_bfloat162 h; unsigned u; } v;
    v.h = __float22bfloat162_rn(make_float2(a, b));
    return v.u;
}
__device__ __forceinline__ short4v pk4(float a, float b, float c, float d) {
    union { unsigned u[2]; short4v s; } v;
    v.u[0] = pkbf(a, b); v.u[1] = pkbf(c, d);
    return v.s;
}
__device__ __forceinline__ short8 mk8(int a, int b, int c, int d) {
    union { int u[4]; short8 s; } v;
    v.u[0] = a; v.u[1] = b; v.u[2] = c; v.u[3] = d;
    return v.s;
}

// async global->LDS, 16B per lane; LDS dst = wave-uniform base + lane*16
__device__ __forceinline__ void async_ld16(const short* g, short* l) {
    __builtin_amdgcn_global_load_lds(
        (const __attribute__((address_space(1))) unsigned int*)g,
        (__attribute__((address_space(3))) unsigned int*)l, 16, 0, 0);
}

// ---------------------------------------------------------------------------
// Prep: fused fp32 -> bf16 conversion over 7 segments (x + 6 weight blobs),
// with a per-segment scale (wq is pre-scaled by SC_LOG2E so attention's
// softmax exp becomes a bare v_exp_f32).
// ---------------------------------------------------------------------------
struct CvtArgs {
    const float* src[7];
    short*       dst[7];
    float        scl[7];
    int          end4[7];   // cumulative segment ends, in float4 units
};

__global__ __launch_bounds__(256)
void cvt_all(CvtArgs a, int total4) {
    const int i = blockIdx.x * 256 + threadIdx.x;
    if (i >= total4) return;
    int s = 0;
    while (i >= a.end4[s]) ++s;
    const int base = s ? a.end4[s - 1] : 0;
    const int j = i - base;
    const float sc = a.scl[s];
    const float4 v = ((const float4*)a.src[s])[j];
    short4v o;
    o[0] = f2bf(v.x * sc); o[1] = f2bf(v.y * sc);
    o[2] = f2bf(v.z * sc); o[3] = f2bf(v.w * sc);
    *(short4v*)(a.dst[s] + (size_t)j * 4) = o;
}

__global__ __launch_bounds__(256)
void concat_bias(const float* __restrict__ bq, const float* __restrict__ bk,
                 const float* __restrict__ bv, float* __restrict__ dst) {
    const int i = blockIdx.x * 256 + threadIdx.x;
    if (i >= QKV_LD) return;
    dst[i] = (i < 768) ? bq[i] * SC_LOG2E : (i < 1536 ? bk[i - 768] : bv[i - 1536]);
}

// ---------------------------------------------------------------------------
// bf16 MFMA GEMM: C[M,N] = A[M,K] @ W[N,K]^T + bias[N]  (optional ReLU)
// Validated stack (R8-R10): 3-stage counted-vmcnt pipeline, LDS XOR-swizzle,
// XCD-aware bijective tile remap. R12's SPLITK REVERTED: f32-partial traffic
// (+38MB/phase ~ +6us each) outweighed any latency gain -- the 3-stage
// pipeline had already covered the K-loop latency (theory falsified by A/B).
// ---------------------------------------------------------------------------
template <int BM, int BN, int BK, typename OutT, bool RELU>
__global__ __launch_bounds__(256)
void gemm_mfma(const short* __restrict__ A, const short* __restrict__ W,
               const float* __restrict__ bias, OutT* __restrict__ C,
               int M, int N, int K) {
    constexpr int MI = BM / 32;   // 16-row tiles per wave
    constexpr int NI = BN / 32;   // 16-col tiles per wave
    constexpr int KI = BK / 32;   // k-substeps per tile
    static_assert(BM * BK == 4096 && BN * BK == 4096, "4 glds/thread/stage");
    constexpr int ROWSTEP = 2048 / BK;   // rows per 2048-short chunk
    __shared__ __align__(16) short As[3][4096];
    __shared__ __align__(16) short Bs[3][4096];

    const int tid  = threadIdx.x;
    const int w    = tid >> 6;
    const int lane = tid & 63;
    const int l16  = lane & 15;
    const int q4   = lane >> 4;          // 0..3

    // XCD-aware bijective tile remap (grids here are all %8 == 0)
    const int gx  = N / BN;
    const int nwg = gx * (M / BM);
    const int lid = blockIdx.x + blockIdx.y * gx;
    const int tile = (lid & 7) * (nwg >> 3) + (lid >> 3);
    const int row0 = (tile / gx) * BM;
    const int col0 = (tile % gx) * BN;

    const int wm   = (w >> 1) * (BM / 2); // wave m-offset in tile
    const int wn   = (w & 1) * (BN / 2);  // wave n-offset in tile

    // swizzled LDS offset (in shorts) of 16B slot j in row r
    auto lds_off = [&](int r, int j) {
        const int xt = (BK == 64) ? (r & 7) : ((r >> 1) & 3);
        return r * BK + (j ^ xt) * 8;
    };

    // staging: thread tid owns LDS slot (row mA, slot sA) of each chunk;
    // load the GLOBAL column that belongs in that swizzled slot.
    const int mA = tid / (BK / 8);
    const int sA = tid % (BK / 8);
    const int xtA = (BK == 64) ? (mA & 7) : ((mA >> 1) & 3);
    const int kA = (sA ^ xtA) * 8;
    const short* gA0 = A + (size_t)(row0 + mA) * K + kA;
    const short* gA1 = gA0 + (size_t)ROWSTEP * K;
    const short* gB0 = W + (size_t)(col0 + mA) * K + kA;
    const short* gB1 = gB0 + (size_t)ROWSTEP * K;

    f32x4 acc[MI][NI];
#pragma unroll
    for (int mi = 0; mi < MI; ++mi)
#pragma unroll
        for (int ni = 0; ni < NI; ++ni)
#pragma unroll
            for (int r = 0; r < 4; ++r) acc[mi][ni][r] = 0.f;

    auto stage = [&](int buf) {
        async_ld16(gA0, &As[buf][w * 512]);
        async_ld16(gA1, &As[buf][2048 + w * 512]);
        async_ld16(gB0, &Bs[buf][w * 512]);
        async_ld16(gB1, &Bs[buf][2048 + w * 512]);
        gA0 += BK; gA1 += BK; gB0 += BK; gB1 += BK;
    };
    auto compute = [&](int buf) {
#pragma unroll
        for (int ks = 0; ks < KI; ++ks) {
            short8 af[MI], bfr[NI];
#pragma unroll
            for (int mi = 0; mi < MI; ++mi)
                af[mi] = *(const short8*)&As[buf][lds_off(wm + mi * 16 + l16, ks * 4 + q4)];
#pragma unroll
            for (int ni = 0; ni < NI; ++ni)
                bfr[ni] = *(const short8*)&Bs[buf][lds_off(wn + ni * 16 + l16, ks * 4 + q4)];
#pragma unroll
            for (int mi = 0; mi < MI; ++mi)
#pragma unroll
                for (int ni = 0; ni < NI; ++ni)
                    acc[mi][ni] = __builtin_amdgcn_mfma_f32_16x16x32_bf16(
                        af[mi], bfr[ni], acc[mi][ni], 0, 0, 0);
        }
    };

    const int NT = K / BK;
    stage(0);                            // prologue: tiles 0,1 in flight
    stage(1);
    int cur = 0;                         // rotating buffer index (t % 3)
    for (int t = 0; t < NT; ++t) {
        if (t + 2 < NT) {
            int nb = cur + 2; if (nb >= 3) nb -= 3;
            stage(nb);                   // 12 outstanding
            asm volatile("s_waitcnt vmcnt(8)" ::: "memory");  // tile t done
        } else if (t + 1 < NT) {
            asm volatile("s_waitcnt vmcnt(4)" ::: "memory");  // tile t done
        } else {
            asm volatile("s_waitcnt vmcnt(0)" ::: "memory");  // final drain
        }
        __builtin_amdgcn_s_barrier();    // all waves: buf[cur] fully written
        __builtin_amdgcn_sched_barrier(0);
        compute(cur);
        __builtin_amdgcn_s_barrier();    // all waves: buf[cur] fully read
        __builtin_amdgcn_sched_barrier(0);
        if (++cur == 3) cur = 0;
    }

    float bcol[NI];
#pragma unroll
    for (int ni = 0; ni < NI; ++ni) bcol[ni] = bias[col0 + wn + ni * 16 + l16];
#pragma unroll
    for (int mi = 0; mi < MI; ++mi) {
#pragma unroll
        for (int r = 0; r < 4; ++r) {
            const int row = row0 + wm + mi * 16 + q4 * 4 + r;
#pragma unroll
            for (int ni = 0; ni < NI; ++ni) {
                float v = acc[mi][ni][r] + bcol[ni];
                if (RELU) v = fmaxf(v, 0.f);
                const int col = col0 + wn + ni * 16 + l16;
                if constexpr (sizeof(OutT) == 2)
                    C[(size_t)row * N + col] = (OutT)f2bf(v);
                else
                    C[(size_t)row * N + col] = v;
            }
        }
    }
}

// ---------------------------------------------------------------------------
// MFMA bf16 flash attention v7 (frozen control): transposed PV +
// in-register P + double-buffered K/V LDS, 1 barrier/iter.
// ---------------------------------------------------------------------------
__global__ __launch_bounds__(256)
void attn_mfma(const short* __restrict__ qkv, short* __restrict__ Opart,
               float* __restrict__ lpart) {
    __shared__ short Ks[2][2][32][56];  // [buf][d-half][key][d%48], conflict-free
    __shared__ short Vt[2][96][44];     // [buf][d][key], stride 44

    const int tid  = threadIdx.x;
    const int w    = tid >> 6;
    const int lane = tid & 63;
    const int l31  = lane & 31;
    const int h5   = lane >> 5;
    const int t0   = blockIdx.x * 128;
    const int bh   = blockIdx.y;
    const int split = blockIdx.z;
    const int b    = bh >> 3;
    const int h    = bh & 7;

    // Q fragments straight from global bf16 (wave-private 32 q-rows)
    short8 qf[6];
    {
        const int qrow = t0 + w * 32 + l31;
        const short* qb = qkv + ((size_t)qrow * B_SZ + b) * QKV_LD + h * HD;
#pragma unroll
        for (int ks = 0; ks < 6; ++ks)
            qf[ks] = *(const short8*)&qb[ks * 16 + h5 * 8];
    }

    // --- staging assignments (wave-specialized), chunk-local keys ---
    const int k_row = tid >> 2;                   // 0..31 (valid for tid<128)
    const int k_q   = tid & 3;                    // d-quarter
    const short* gK = qkv + ((size_t)(split * CHUNK + k_row) * B_SZ + b) * QKV_LD
                      + D_DIM + h * HD + k_q * 24;
    const int ll = tid - 128;
    const int dg = (ll & 7) * 12;                 // d-group
    const int kg = (ll >> 3) * 2;                 // key pair
    const short* gV = qkv + ((size_t)(split * CHUNK + kg) * B_SZ + b) * QKV_LD
                      + 2 * D_DIM + h * HD + dg;
    const size_t step  = (size_t)32 * B_SZ * QKV_LD;
    const size_t vrow  = (size_t)B_SZ * QKV_LD;   // one key row

    f32x16 oacc[3];
#pragma unroll
    for (int nt = 0; nt < 3; ++nt)
#pragma unroll
        for (int r = 0; r < 16; ++r) oacc[nt][r] = 0.f;
    float dsum = 0.f;

    short8  kpf[3];
    short4v vpf[2][3];
    auto prefetch = [&](int t) {
        const size_t off = (size_t)t * step;
        if (w < 2) {
#pragma unroll
            for (int j = 0; j < 3; ++j)
                kpf[j] = *(const short8*)(gK + off + j * 8);
        } else {
#pragma unroll
            for (int r = 0; r < 2; ++r)
#pragma unroll
                for (int c = 0; c < 3; ++c)
                    vpf[r][c] = *(const short4v*)(gV + off + r * vrow + c * 4);
        }
    };
    auto lds_write = [&](int buf) {
        if (w < 2) {
#pragma unroll
            for (int j = 0; j < 3; ++j)
                *(short8*)&Ks[buf][k_q >> 1][k_row][(k_q & 1) * 24 + j * 8] = kpf[j];
        } else {
#pragma unroll
            for (int d = 0; d < 12; ++d) {
                short2v t;
                t[0] = vpf[0][d >> 2][d & 3];
                t[1] = vpf[1][d >> 2][d & 3];
                *(short2v*)&Vt[buf][dg + d][kg] = t;
            }
        }
    };

    constexpr int NIT = CHUNK / 32;   // 16
    prefetch(0);
    lds_write(0);        // tile 0 -> buf0 (no prior readers)
    prefetch(1);

    for (int it = 0; it < NIT; ++it) {
        __syncthreads();   // buf[it&1] writes visible; buf[(it+1)&1] readers done
        if (it + 1 < NIT) lds_write((it + 1) & 1);   // overlaps this tile's MFMA
        if (it + 2 < NIT) prefetch(it + 2);          // HBM latency under compute
        const int pb = it & 1;

        // S^T = K.Q^T (swapped operands; Q pre-scaled by scale*log2e).
        // sa[r] = S[q=l31][key=(r&3)+8*(r>>2)+4*h5]
        f32x16 sa;
#pragma unroll
        for (int r = 0; r < 16; ++r) sa[r] = 0.f;
        __builtin_amdgcn_s_setprio(1);
#pragma unroll
        for (int ks = 0; ks < 6; ++ks) {
            const int half = ks / 3;                   // compile-time per ks
            const int base = ks * 16 - half * 48;      // local d within half
            const short8 kf = *(const short8*)&Ks[pb][half][l31][base + h5 * 8];
            sa = __builtin_amdgcn_mfma_f32_32x32x16_bf16(kf, qf[ks], sa, 0, 0, 0);
        }
        __builtin_amdgcn_s_setprio(0);

        // P = 2^S (bare v_exp), fully in-register
        float pvx[16];
#pragma unroll
        for (int r = 0; r < 16; ++r) pvx[r] = __builtin_amdgcn_exp2f(sa[r]);
        // denominator partial (this lane's 16 keys of the tile)
        dsum += ((pvx[0] + pvx[1]) + (pvx[2] + pvx[3]))
              + ((pvx[4] + pvx[5]) + (pvx[6] + pvx[7]))
              + ((pvx[8] + pvx[9]) + (pvx[10] + pvx[11]))
              + ((pvx[12] + pvx[13]) + (pvx[14] + pvx[15]));

        // pack to bf16 + permlane32_swap -> P^T B-fragments (keys 0..15, 16..31)
        int wA0 = (int)pkbf(pvx[0],  pvx[1]);
        int wA1 = (int)pkbf(pvx[2],  pvx[3]);
        int wA2 = (int)pkbf(pvx[4],  pvx[5]);
        int wA3 = (int)pkbf(pvx[6],  pvx[7]);
        int wB0 = (int)pkbf(pvx[8],  pvx[9]);
        int wB1 = (int)pkbf(pvx[10], pvx[11]);
        int wB2 = (int)pkbf(pvx[12], pvx[13]);
        int wB3 = (int)pkbf(pvx[14], pvx[15]);
        const int2v s0 = __builtin_amdgcn_permlane32_swap(wA0, wA2, false, false);
        const int2v s1 = __builtin_amdgcn_permlane32_swap(wA1, wA3, false, false);
        const int2v s2 = __builtin_amdgcn_permlane32_swap(wB0, wB2, false, false);
        const int2v s3 = __builtin_amdgcn_permlane32_swap(wB1, wB3, false, false);
        const short8 pf0 = mk8(s0[0], s1[0], s0[1], s1[1]);  // keys 0..15
        const short8 pf1 = mk8(s2[0], s3[0], s2[1], s3[1]);  // keys 16..31

        // O^T += V^T . P^T  (3 d-tiles of 32)
        __builtin_amdgcn_s_setprio(1);
#pragma unroll
        for (int ks2 = 0; ks2 < 2; ++ks2) {
            const short8 pfr = ks2 ? pf1 : pf0;
#pragma unroll
            for (int nt = 0; nt < 3; ++nt) {
                const short* vp = &Vt[pb][nt * 32 + l31][ks2 * 16 + h5 * 8];
                const short4v vlo = *(const short4v*)vp;
                const short4v vhi = *(const short4v*)(vp + 4);
                const short8 vf = __builtin_shufflevector(vlo, vhi, 0, 1, 2, 3, 4, 5, 6, 7);
                oacc[nt] = __builtin_amdgcn_mfma_f32_32x32x16_bf16(vf, pfr, oacc[nt], 0, 0, 0);
            }
        }
        __builtin_amdgcn_s_setprio(0);
    }

    // epilogue: lane l31 = q-row; oacc[nt][r] = O^T[d=nt*32+(r&3)+8*(r>>2)+4*h5][q]
    const float other = __shfl_xor(dsum, 32);
    const float denom = dsum + other;
    const int qrow = t0 + w * 32 + l31;
    const int grow = qrow * B_SZ + b;
    short* op = Opart + ((size_t)split * TB + grow) * D_DIM + h * HD;
#pragma unroll
    for (int nt = 0; nt < 3; ++nt)
#pragma unroll
        for (int g = 0; g < 4; ++g)
            *(short4v*)&op[nt * 32 + g * 8 + h5 * 4] =
                pk4(oacc[nt][4 * g], oacc[nt][4 * g + 1],
                    oacc[nt][4 * g + 2], oacc[nt][4 * g + 3]);
    if (lane < 32)
        lpart[((size_t)split * TB + grow) * H_NUM + h] = denom;
}

// ---------------------------------------------------------------------------
// Combine: ctx = (sum_c Opart[c]) / (sum_c lpart[c]).  One block per row,
// 192 active lanes x 4 d each, short4 vector loads.
// ---------------------------------------------------------------------------
__global__ __launch_bounds__(256)
void attn_combine(const short* __restrict__ Opart, const float* __restrict__ lpart,
                  short* __restrict__ ctx) {
    const int row = blockIdx.x;
    const int tid = threadIdx.x;
    if (tid >= 192) return;
    const int d = tid * 4;
    const int h = d / 96;
    float o0 = 0.f, o1 = 0.f, o2 = 0.f, o3 = 0.f, l = 0.f;
#pragma unroll
    for (int c = 0; c < NSPLIT; ++c) {
        const short4v v = *(const short4v*)&Opart[((size_t)c * TB + row) * D_DIM + d];
        o0 += bf2f(v[0]); o1 += bf2f(v[1]); o2 += bf2f(v[2]); o3 += bf2f(v[3]);
        l += lpart[((size_t)c * TB + row) * H_NUM + h];
    }
    const float iv = 1.f / l;
    short4v r;
    r[0] = f2bf(o0 * iv); r[1] = f2bf(o1 * iv);
    r[2] = f2bf(o2 * iv); r[3] = f2bf(o3 * iv);
    *(short4v*)&ctx[(size_t)row * D_DIM + d] = r;
}

// ---------------------------------------------------------------------------
// Fused residual + LayerNorm: out = LN(xres + y)*g + b.
// ---------------------------------------------------------------------------
template <typename XT, typename OT>
__global__ __launch_bounds__(256)
void ln_residual(const XT* __restrict__ xres, const short* __restrict__ y,
                 const float* __restrict__ g, const float* __restrict__ bb,
                 OT* __restrict__ out) {
    const int row = blockIdx.x;
    const int tid = threadIdx.x;
    const XT*    xr = xres + (size_t)row * D_DIM;
    const short* yr = y + (size_t)row * D_DIM;

    float vals[3];
    float s = 0.f, s2 = 0.f;
#pragma unroll
    for (int i = 0; i < 3; ++i) {
        const int d = tid + i * 256;
        float xv;
        if constexpr (sizeof(XT) == 2) xv = bf2f((short)xr[d]);
        else                           xv = (float)xr[d];
        const float t = xv + bf2f(yr[d]);
        vals[i] = t;
        s += t;
        s2 = fmaf(t, t, s2);
    }
#pragma unroll
    for (int off = 32; off > 0; off >>= 1) {
        s  += __shfl_down(s, off);
        s2 += __shfl_down(s2, off);
    }
    __shared__ float red_s[4], red_s2[4];
    const int wid = tid >> 6, lane = tid & 63;
    if (lane == 0) { red_s[wid] = s; red_s2[wid] = s2; }
    __syncthreads();
    __shared__ float sh_mean, sh_rstd;
    if (tid == 0) {
        const float ts  = red_s[0] + red_s[1] + red_s[2] + red_s[3];
        const float ts2 = red_s2[0] + red_s2[1] + red_s2[2] + red_s2[3];
        const float mean = ts * (1.f / D_DIM);
        const float var  = ts2 * (1.f / D_DIM) - mean * mean;
        sh_mean = mean;
        sh_rstd = rsqrtf(var + EPS);
    }
    __syncthreads();
    const float mean = sh_mean, rstd = sh_rstd;
#pragma unroll
    for (int i = 0; i < 3; ++i) {
        const int d = tid + i * 256;
        const float o = (vals[i] - mean) * rstd * g[d] + bb[d];
        if constexpr (sizeof(OT) == 2)
            out[(size_t)row * D_DIM + d] = (OT)f2bf(o);
        else
            out[(size_t)row * D_DIM + d] = o;
    }
}

// ---------------------------------------------------------------------------
// Launch
// ---------------------------------------------------------------------------
extern "C" void kernel_launch(void* const* d_in, const int* in_sizes, int n_in,
                              void* d_out, int out_size, void* d_ws, size_t ws_size,
                              hipStream_t stream) {
    const float* x     = (const float*)d_in[0];
    const float* wq    = (const float*)d_in[1];
    const float* bq    = (const float*)d_in[2];
    const float* wk    = (const float*)d_in[3];
    const float* bk    = (const float*)d_in[4];
    const float* wv    = (const float*)d_in[5];
    const float* bv    = (const float*)d_in[6];
    const float* wo    = (const float*)d_in[7];
    const float* bo    = (const float*)d_in[8];
    const float* ln1g  = (const float*)d_in[9];
    const float* ln1b  = (const float*)d_in[10];
    const float* w1    = (const float*)d_in[11];
    const float* b1    = (const float*)d_in[12];
    const float* w2    = (const float*)d_in[13];
    const float* b2    = (const float*)d_in[14];
    const float* ln2g  = (const float*)d_in[15];
    const float* ln2b  = (const float*)d_in[16];
    float* out = (float*)d_out;

    // workspace layout (bytes) — total 65,020,928
    char* ws = (char*)d_ws;
    short* qkvb  = (short*)(ws + 0);             // [TB,2304] bf16  0 .. 18,874,368
    short* ctxb  = (short*)(ws + 18874368);      // [TB,768]  bf16  .. 25,165,824
    short* hb    = (short*)(ws + 0);             // [TB,3072] bf16  (reuses qkvb+ctxb)
    short* xb    = (short*)(ws + 25165824);      // [TB,768]  bf16  .. 31,457,280
    short* Opart = (short*)(ws + 25165824);      // 4x[TB,768] bf16 .. 50,331,648 (over xb)
    float* lpart = (float*)(ws + 50331648);      // 4x[TB,8]  f32   .. 50,855,936
    short* tmpb  = (short*)(ws + 25165824);      // [TB,768]  bf16  (over dead Opart)
    short* x1b   = (short*)(ws + 31457280);      // [TB,768]  bf16  (over dead Opart)
    short* wqkv  = (short*)(ws + 50855936);      // [2304,768] bf16 .. 54,394,880
    short* wob   = (short*)(ws + 54394880);      // [768,768]  bf16 .. 55,574,528
    short* w1b   = (short*)(ws + 55574528);      // [3072,768] bf16 .. 60,293,120
    short* w2b   = (short*)(ws + 60293120);      // [768,3072] bf16 .. 65,011,712
    float* bqkv  = (float*)(ws + 65011712);      // [2304] f32      .. 65,020,928

    // fused fp32->bf16 conversions (wq pre-scaled by scale*log2e)
    CvtArgs ca;
    ca.src[0] = x;  ca.dst[0] = xb;   ca.scl[0] = 1.f;
    ca.src[1] = wq; ca.dst[1] = wqkv; ca.scl[1] = SC_LOG2E;
    ca.src[2] = wk; ca.dst[2] = wqkv + 768 * 768;     ca.scl[2] = 1.f;
    ca.src[3] = wv; ca.dst[3] = wqkv + 2 * 768 * 768; ca.scl[3] = 1.f;
    ca.src[4] = wo; ca.dst[4] = wob;  ca.scl[4] = 1.f;
    ca.src[5] = w1; ca.dst[5] = w1b;  ca.scl[5] = 1.f;
    ca.src[6] = w2; ca.dst[6] = w2b;  ca.scl[6] = 1.f;
    const int n4[7] = {TB * D_DIM / 4, 768 * 768 / 4, 768 * 768 / 4, 768 * 768 / 4,
                       768 * 768 / 4, FFN * 768 / 4, 768 * FFN / 4};
    int acc4 = 0;
    for (int i = 0; i < 7; ++i) { acc4 += n4[i]; ca.end4[i] = acc4; }
    cvt_all<<<(acc4 + 255) / 256, 256, 0, stream>>>(ca, acc4);
    concat_bias<<<(QKV_LD + 255) / 256, 256, 0, stream>>>(bq, bk, bv, bqkv);

    // fused QKV projection: [TB,2304] = xb @ wqkv^T + bqkv (576 blocks, %8==0)
    gemm_mfma<128, 128, 32, short, false><<<dim3(QKV_LD / 128, TB / 128), 256, 0, stream>>>(
        xb, wqkv, bqkv, qkvb, TB, QKV_LD, D_DIM);

    // attention (v7, frozen) + combine
    attn_mfma<<<dim3(T_LEN / 128, B_SZ * H_NUM, NSPLIT), dim3(256), 0, stream>>>(
        qkvb, Opart, lpart);
    attn_combine<<<dim3(TB), 256, 0, stream>>>(Opart, lpart, ctxb);

    // out projection: BM=64/BK=64 -> 768 blocks, swizzled LDS + XCD swizzle
    gemm_mfma<64, 64, 64, short, false><<<dim3(D_DIM / 64, TB / 64), 256, 0, stream>>>(
        ctxb, wob, bo, tmpb, TB, D_DIM, D_DIM);
    ln_residual<float, short><<<dim3(TB), 256, 0, stream>>>(x, tmpb, ln1g, ln1b, x1b);

    // FFN1 (768 blocks)
    gemm_mfma<128, 128, 32, short, true><<<dim3(FFN / 128, TB / 128), 256, 0, stream>>>(
        x1b, w1b, b1, hb, TB, FFN, D_DIM);
    // FFN2 (768 blocks)
    gemm_mfma<64, 64, 64, short, false><<<dim3(D_DIM / 64, TB / 64), 256, 0, stream>>>(
        hb, w2b, b2, tmpb, TB, D_DIM, FFN);
    ln_residual<short, float><<<dim3(TB), 256, 0, stream>>>(x1b, tmpb, ln2g, ln2b, out);
}